// Round 5
// baseline (5485.871 us; speedup 1.0000x reference)
//
#include <hip/hip_runtime.h>
#include <math.h>

// ---------- Problem constants ----------
#define N_NODES 65536
#define B_GR    8
#define EMB_N   512
#define E_EDGES 458752     // N * 7
#define NSEG    458752     // N * 7 segments (row*7 + etype)
#define EPS     1e-5f

typedef unsigned short u16;
typedef unsigned int   u32;

__device__ __forceinline__ float bf2f(u16 u) {
    u32 x = ((u32)u) << 16; float f; __builtin_memcpy(&f, &x, 4); return f;
}
__device__ __forceinline__ u16 f2bf(float f) {
    u32 x; __builtin_memcpy(&x, &f, 4);
    u32 r = x + 0x7fffu + ((x >> 16) & 1u);
    return (u16)(r >> 16);
}

// ---------- zero scratch (hist + S + Q) ----------
__global__ __launch_bounds__(256) void zero_kernel(int* __restrict__ hist,
                                                   float* __restrict__ S, float* __restrict__ Q) {
    int i = blockIdx.x * 256 + threadIdx.x;
    if (i < NSEG) hist[i] = 0;
    if (i < 2048) { S[i] = 0.f; Q[i] = 0.f; }
}
__global__ __launch_bounds__(256) void zero_sq_kernel(float* __restrict__ S, float* __restrict__ Q) {
    int i = blockIdx.x * 256 + threadIdx.x;
    if (i < 2048) { S[i] = 0.f; Q[i] = 0.f; }
}

// ---------- emb GEMM: embout[b][n] = silu(emb[b]) @ emb_w + emb_b ----------
__global__ __launch_bounds__(256) void emb_kernel(
    const float* __restrict__ emb, const float* __restrict__ embw,
    const float* __restrict__ embb, float* __restrict__ embout)
{
    __shared__ float semb[B_GR * EMB_N];
    int tid = threadIdx.x;
    for (int i = tid; i < B_GR * EMB_N; i += 256) {
        float e = emb[i];
        semb[i] = e / (1.f + expf(-e));
    }
    __syncthreads();
    float bb = embb[tid];
    float acc[8];
#pragma unroll
    for (int b = 0; b < 8; b++) acc[b] = bb;
    for (int k = 0; k < EMB_N; k++) {
        float wv = embw[k * 256 + tid];
#pragma unroll
        for (int b = 0; b < 8; b++) acc[b] += semb[b * EMB_N + k] * wv;
    }
#pragma unroll
    for (int b = 0; b < 8; b++) embout[b * 256 + tid] = acc[b];
}

// ---------- group-norm stats: per (batch, channel) sums ----------
__global__ __launch_bounds__(256) void stats_kernel(const float* __restrict__ xin,
                                                    const int* __restrict__ batch_id,
                                                    float* __restrict__ S, float* __restrict__ Q) {
    int c = threadIdx.x;
    int n0 = blockIdx.x * 64;
    float s = 0.f, q = 0.f;
    int bcur = batch_id[n0];
    for (int r = 0; r < 64; r++) {
        int n = n0 + r;
        int b = batch_id[n];
        if (b != bcur) {
            atomicAdd(&S[bcur * 256 + c], s);
            atomicAdd(&Q[bcur * 256 + c], q);
            s = 0.f; q = 0.f; bcur = b;
        }
        float v = xin[(size_t)n * 256 + c];
        s += v;
        q = fmaf(v, v, q);
    }
    atomicAdd(&S[bcur * 256 + c], s);
    atomicAdd(&Q[bcur * 256 + c], q);
}

// ---------- finalize: counts + per-(b,group) mean / inv_std ----------
__global__ __launch_bounds__(256) void finalize_kernel(const int* __restrict__ batch_id,
                                                       const float* __restrict__ S, const float* __restrict__ Q,
                                                       float* __restrict__ gmean, float* __restrict__ gistd) {
    __shared__ int scnt[8];
    int tid = threadIdx.x;
    if (tid < 8) scnt[tid] = 0;
    __syncthreads();
    int c0=0,c1=0,c2=0,c3=0,c4=0,c5=0,c6=0,c7=0;
    for (int i = tid; i < N_NODES; i += 256) {
        int b = batch_id[i];
        c0 += (b==0); c1 += (b==1); c2 += (b==2); c3 += (b==3);
        c4 += (b==4); c5 += (b==5); c6 += (b==6); c7 += (b==7);
    }
    atomicAdd(&scnt[0], c0); atomicAdd(&scnt[1], c1); atomicAdd(&scnt[2], c2); atomicAdd(&scnt[3], c3);
    atomicAdd(&scnt[4], c4); atomicAdd(&scnt[5], c5); atomicAdd(&scnt[6], c6); atomicAdd(&scnt[7], c7);
    __syncthreads();
    int b = tid >> 5, g = tid & 31;
    float Sg = 0.f, Qg = 0.f;
#pragma unroll
    for (int k = 0; k < 8; k++) {
        Sg += S[b * 256 + g * 8 + k];
        Qg += Q[b * 256 + g * 8 + k];
    }
    float cnt8 = (float)scnt[b] * 8.f;
    float D = cnt8 + EPS;                      // matches reference: count*cpg + EPS
    float m = Sg / D;
    float var = (Qg - 2.f * m * Sg + cnt8 * m * m) / D;
    float istd = rsqrtf(var + EPS);
    gmean[tid] = m;      // tid = b*32+g
    gistd[tid] = istd;
}

// ---------- normalize + affine + SiLU: f32 in -> bf16 y ----------
__global__ __launch_bounds__(256) void norm_silu_kernel(const float* __restrict__ xin,
                                                        const int* __restrict__ batch_id,
                                                        const float* __restrict__ gmean, const float* __restrict__ gistd,
                                                        const float* __restrict__ w, const float* __restrict__ bias,
                                                        u16* __restrict__ yout) {
    int tid = threadIdx.x;
    int n = blockIdx.x * 8 + (tid >> 5);
    int g = tid & 31;
    int c0 = g * 8;
    int b = batch_id[n];
    float m = gmean[b * 32 + g], is = gistd[b * 32 + g];
#pragma unroll
    for (int k = 0; k < 8; k++) {
        float v = (xin[(size_t)n * 256 + c0 + k] - m) * is;
        v = v * w[c0 + k] + bias[c0 + k];
        v = v / (1.f + expf(-v));
        yout[(size_t)n * 256 + c0 + k] = f2bf(v);
    }
}

// ---------- CSR build ----------
__global__ __launch_bounds__(256) void hist_kernel(const int* __restrict__ ei, const int* __restrict__ et,
                                                   int* __restrict__ hist) {
    int e = blockIdx.x * 256 + threadIdx.x;
    if (e >= E_EDGES) return;
    int s = ei[e] * 7 + et[e];
    atomicAdd(&hist[s], 1);
}

__global__ __launch_bounds__(512) void scan1_kernel(const int* __restrict__ hist, int* __restrict__ partials) {
    __shared__ int sd[512];
    int i = blockIdx.x * 512 + threadIdx.x;
    sd[threadIdx.x] = hist[i];
    __syncthreads();
    for (int off = 256; off > 0; off >>= 1) {
        if (threadIdx.x < off) sd[threadIdx.x] += sd[threadIdx.x + off];
        __syncthreads();
    }
    if (threadIdx.x == 0) partials[blockIdx.x] = sd[0];
}

__global__ __launch_bounds__(1024) void scan2_kernel(int* __restrict__ partials) {
    __shared__ int sd[1024];
    int t = threadIdx.x;
    int v = (t < 896) ? partials[t] : 0;
    sd[t] = v;
    __syncthreads();
    for (int off = 1; off < 1024; off <<= 1) {
        int u = (t >= off) ? sd[t - off] : 0;
        __syncthreads();
        sd[t] += u;
        __syncthreads();
    }
    if (t < 896) partials[t] = sd[t] - v;   // exclusive
}

// In-place: reads hist[i], writes offsets over the same buffer.
__global__ __launch_bounds__(512) void scan3_kernel(int* __restrict__ hist_offs, const int* __restrict__ partials,
                                                    int* __restrict__ cursor) {
    __shared__ int sd[512];
    int t = threadIdx.x;
    int i = blockIdx.x * 512 + t;
    int c = hist_offs[i];
    sd[t] = c;
    __syncthreads();
    for (int off = 1; off < 512; off <<= 1) {
        int u = (t >= off) ? sd[t - off] : 0;
        __syncthreads();
        sd[t] += u;
        __syncthreads();
    }
    int o = partials[blockIdx.x] + sd[t] - c;
    hist_offs[i] = o;
    cursor[i] = o;
}

__global__ __launch_bounds__(256) void fill_kernel(const int* __restrict__ ei, const int* __restrict__ et,
                                                   int* __restrict__ cursor, int* __restrict__ elist) {
    int e = blockIdx.x * 256 + threadIdx.x;
    if (e >= E_EDGES) return;
    int s = ei[e] * 7 + et[e];
    int p = atomicAdd(&cursor[s], 1);
    if (p >= 0 && p < E_EDGES) elist[p] = ei[E_EDGES + e];   // col
}

// ---------- simple conv: one block per node, f32, native W layout ----------
// out[m][n] = sum_t sum_c agg[t][c] * W[(t*263+c)*256 + n] + add-term
//   agg[t][c<256] = sum over edges of segment (m,t) of y[col][c]
//   agg[t][256+j] = count of neighbors with node_type == j
// mode 0: + embout[batch_id[m]][n]   (h2, written to d_out)
// mode 1: + x[m][n]                  (final output)
__global__ __launch_bounds__(256) void conv_kernel(
    const u16* __restrict__ y, const float* __restrict__ W,
    const int* __restrict__ offs, const int* __restrict__ cursor,
    const int* __restrict__ elist, const int* __restrict__ node_type,
    const int* __restrict__ batch_id, const float* __restrict__ embout,
    const float* __restrict__ xres, float* __restrict__ out, int mode)
{
    __shared__ float agg[7 * 264];
    int m = blockIdx.x, tid = threadIdx.x;
    for (int i = tid; i < 7 * 264; i += 256) agg[i] = 0.f;
    __syncthreads();
    for (int t = 0; t < 7; t++) {
        int s = m * 7 + t;
        int start = offs[s], end = cursor[s];
        start = start < 0 ? 0 : (start > E_EDGES ? E_EDGES : start);
        end   = end < start ? start : (end > E_EDGES ? E_EDGES : end);
        for (int e = start; e < end; e++) {
            int col = elist[e] & (N_NODES - 1);
            agg[t * 264 + tid] += bf2f(y[(size_t)col * 256 + tid]);
            if (tid < 7) agg[t * 264 + 256 + tid] += (node_type[col] == tid) ? 1.f : 0.f;
        }
    }
    __syncthreads();
    float acc;
    if (mode == 0) acc = embout[batch_id[m] * 256 + tid];
    else           acc = xres[(size_t)m * 256 + tid];
    for (int t = 0; t < 7; t++) {
        int s = m * 7 + t;
        if (cursor[s] <= offs[s]) continue;     // empty segment -> zero contribution
        const float* Wp = W + (size_t)t * 263 * 256 + tid;
        const float* ap = &agg[t * 264];
        for (int c = 0; c < 263; c++)
            acc += ap[c] * Wp[(size_t)c * 256];
    }
    out[(size_t)m * 256 + tid] = acc;
}

// ---------- host ----------
extern "C" void kernel_launch(void* const* d_in, const int* in_sizes, int n_in,
                              void* d_out, int out_size, void* d_ws, size_t ws_size,
                              hipStream_t stream) {
    // All float tensors are FLOAT32 per the reference (jnp.float32 throughout).
    // Rounds 0-4 read them as bf16 -> low-u16 of f32 mantissas decode as
    // NaN/Inf bf16s with p~2^-8 -> deterministic NaN. This round: f32 lens.
    const float* x    = (const float*)d_in[0];
    const float* emb  = (const float*)d_in[1];
    const int* bid    = (const int*)d_in[2];
    const int* ei     = (const int*)d_in[3];
    const int* et     = (const int*)d_in[4];
    const int* ntp    = (const int*)d_in[5];
    const float* gn1w = (const float*)d_in[6];
    const float* gn1b = (const float*)d_in[7];
    const float* w1   = (const float*)d_in[8];
    const float* embw = (const float*)d_in[9];
    const float* embb = (const float*)d_in[10];
    const float* gn2w = (const float*)d_in[11];
    const float* gn2b = (const float*)d_in[12];
    const float* w2   = (const float*)d_in[13];
    float* out = (float*)d_out;

    char* p = (char*)d_ws;
    size_t off = 0;
    auto nxt = [&](size_t bytes) -> void* {
        void* r = p + off;
        off += (bytes + 255) & ~(size_t)255;
        return r;
    };
    // ws budget ~41 MB
    u16*   y       = (u16*)nxt((size_t)N_NODES * 256 * 2);     // 33.5 MB (bf16 stage)
    float* embout  = (float*)nxt(8 * 256 * 4);
    float* S       = (float*)nxt(2048 * 4);
    float* Q       = (float*)nxt(2048 * 4);
    float* gmean   = (float*)nxt(256 * 4);
    float* gistd   = (float*)nxt(256 * 4);
    int*   offs    = (int*)nxt((size_t)NSEG * 4);              // hist, then offsets in place
    int*   cursor  = (int*)nxt((size_t)NSEG * 4);
    int*   parts   = (int*)nxt(1024 * 4);
    int*   elist   = (int*)nxt((size_t)E_EDGES * 4);
    float* h2      = out;   // d_out doubles as h2 (dead before final write)
    (void)ws_size; (void)in_sizes; (void)n_in; (void)out_size;

    // 1. zero hist + S/Q
    zero_kernel<<<1792, 256, 0, stream>>>(offs, S, Q);
    // 2. emb GEMM
    emb_kernel<<<1, 256, 0, stream>>>(emb, embw, embb, embout);
    // 3-5. GN1 + SiLU -> y
    stats_kernel<<<1024, 256, 0, stream>>>(x, bid, S, Q);
    finalize_kernel<<<1, 256, 0, stream>>>(bid, S, Q, gmean, gistd);
    norm_silu_kernel<<<8192, 256, 0, stream>>>(x, bid, gmean, gistd, gn1w, gn1b, y);
    // 6-10. CSR build (shared by both convs)
    hist_kernel<<<1792, 256, 0, stream>>>(ei, et, offs);
    scan1_kernel<<<896, 512, 0, stream>>>(offs, parts);
    scan2_kernel<<<1, 1024, 0, stream>>>(parts);
    scan3_kernel<<<896, 512, 0, stream>>>(offs, parts, cursor);
    fill_kernel<<<1792, 256, 0, stream>>>(ei, et, cursor, elist);
    // 11. conv1 (+emb) -> h2 (in d_out)
    conv_kernel<<<N_NODES, 256, 0, stream>>>(y, w1, offs, cursor, elist, ntp, bid, embout, x, h2, 0);
    // 12-14. GN2 + SiLU -> y
    zero_sq_kernel<<<8, 256, 0, stream>>>(S, Q);
    stats_kernel<<<1024, 256, 0, stream>>>(h2, bid, S, Q);
    finalize_kernel<<<1, 256, 0, stream>>>(bid, S, Q, gmean, gistd);
    norm_silu_kernel<<<8192, 256, 0, stream>>>(h2, bid, gmean, gistd, gn2w, gn2b, y);
    // 15. conv2 (+x skip) -> out
    conv_kernel<<<N_NODES, 256, 0, stream>>>(y, w2, offs, cursor, elist, ntp, bid, embout, x, out, 1);
}

// Round 6
// 878.389 us; speedup vs baseline: 6.2454x; 6.2454x over previous
//
#include <hip/hip_runtime.h>
#include <math.h>

// ---------- Problem constants ----------
#define N_NODES 65536
#define B_GR    8
#define EMB_N   512
#define E_EDGES 458752     // N * 7
#define NSEG    458752     // N * 7 segments (row*7 + etype)
#define TSTRIDE 288        // per-type padded K (263 used: 256 feat + 7 onehot)
#define GK      2016       // 7 * 288, multiple of 32
#define EPS     1e-5f

typedef unsigned short u16;
typedef unsigned int   u32;
typedef __bf16 bf16x8 __attribute__((ext_vector_type(8)));
typedef float  f32x4  __attribute__((ext_vector_type(4)));
typedef u16    u16x8  __attribute__((ext_vector_type(8)));

__device__ __forceinline__ float bf2f(u16 u) {
    u32 x = ((u32)u) << 16; float f; __builtin_memcpy(&f, &x, 4); return f;
}
__device__ __forceinline__ u16 f2bf(float f) {
    u32 x; __builtin_memcpy(&x, &f, 4);
    u32 r = x + 0x7fffu + ((x >> 16) & 1u);
    return (u16)(r >> 16);
}

// ---------- zero scratch (hist + S + Q) ----------
__global__ __launch_bounds__(256) void zero_kernel(int* __restrict__ hist,
                                                   float* __restrict__ S, float* __restrict__ Q) {
    int i = blockIdx.x * 256 + threadIdx.x;
    if (i < NSEG) hist[i] = 0;
    if (i < 2048) { S[i] = 0.f; Q[i] = 0.f; }
}
__global__ __launch_bounds__(256) void zero_sq_kernel(float* __restrict__ S, float* __restrict__ Q) {
    int i = blockIdx.x * 256 + threadIdx.x;
    if (i < 2048) { S[i] = 0.f; Q[i] = 0.f; }
}

// ---------- weight transpose+pad (f32 -> bf16)  and  emb GEMM ----------
// Wt[n][t*288+c] = bf16(W[(t*263+c)*256 + n])  (c<263, else 0)
__global__ __launch_bounds__(256) void prep_kernel(
    const float* __restrict__ w1, const float* __restrict__ w2,
    u16* __restrict__ Wt1, u16* __restrict__ Wt2,
    const float* __restrict__ emb, const float* __restrict__ embw,
    const float* __restrict__ embb, float* __restrict__ embout)
{
    int bid = blockIdx.x, tid = threadIdx.x;
    if (bid < 4032) {
        const float* Win = (bid < 2016) ? w1 : w2;
        u16* Wt = (bid < 2016) ? Wt1 : Wt2;
        int idx = (bid % 2016) * 256 + tid;          // over 256*2016 outputs
        int n = idx / GK;
        int k = idx - n * GK;
        int t = k / TSTRIDE;
        int c = k - t * TSTRIDE;
        u16 v = (c < 263) ? f2bf(Win[(size_t)(t * 263 + c) * 256 + n]) : (u16)0;
        Wt[idx] = v;
    } else {
        __shared__ float semb[B_GR * EMB_N];
        for (int i = tid; i < B_GR * EMB_N; i += 256) {
            float e = emb[i];
            semb[i] = e / (1.f + expf(-e));
        }
        __syncthreads();
        float acc[8];
        float bb = embb[tid];
#pragma unroll
        for (int b = 0; b < 8; b++) acc[b] = bb;
        for (int k = 0; k < EMB_N; k++) {
            float wv = embw[k * 256 + tid];
#pragma unroll
            for (int b = 0; b < 8; b++) acc[b] += semb[b * EMB_N + k] * wv;
        }
#pragma unroll
        for (int b = 0; b < 8; b++) embout[b * 256 + tid] = acc[b];
    }
}

// ---------- group-norm stats: per (batch, channel) sums ----------
__global__ __launch_bounds__(256) void stats_kernel(const float* __restrict__ xin,
                                                    const int* __restrict__ batch_id,
                                                    float* __restrict__ S, float* __restrict__ Q) {
    int c = threadIdx.x;
    int n0 = blockIdx.x * 64;
    float s = 0.f, q = 0.f;
    int bcur = batch_id[n0];
    for (int r = 0; r < 64; r++) {
        int n = n0 + r;
        int b = batch_id[n];
        if (b != bcur) {
            atomicAdd(&S[bcur * 256 + c], s);
            atomicAdd(&Q[bcur * 256 + c], q);
            s = 0.f; q = 0.f; bcur = b;
        }
        float v = xin[(size_t)n * 256 + c];
        s += v;
        q = fmaf(v, v, q);
    }
    atomicAdd(&S[bcur * 256 + c], s);
    atomicAdd(&Q[bcur * 256 + c], q);
}

// ---------- finalize: counts + per-(b,group) mean / inv_std ----------
__global__ __launch_bounds__(256) void finalize_kernel(const int* __restrict__ batch_id,
                                                       const float* __restrict__ S, const float* __restrict__ Q,
                                                       float* __restrict__ gmean, float* __restrict__ gistd) {
    __shared__ int scnt[8];
    int tid = threadIdx.x;
    if (tid < 8) scnt[tid] = 0;
    __syncthreads();
    int c0=0,c1=0,c2=0,c3=0,c4=0,c5=0,c6=0,c7=0;
    for (int i = tid; i < N_NODES; i += 256) {
        int b = batch_id[i];
        c0 += (b==0); c1 += (b==1); c2 += (b==2); c3 += (b==3);
        c4 += (b==4); c5 += (b==5); c6 += (b==6); c7 += (b==7);
    }
    atomicAdd(&scnt[0], c0); atomicAdd(&scnt[1], c1); atomicAdd(&scnt[2], c2); atomicAdd(&scnt[3], c3);
    atomicAdd(&scnt[4], c4); atomicAdd(&scnt[5], c5); atomicAdd(&scnt[6], c6); atomicAdd(&scnt[7], c7);
    __syncthreads();
    int b = tid >> 5, g = tid & 31;
    float Sg = 0.f, Qg = 0.f;
#pragma unroll
    for (int k = 0; k < 8; k++) {
        Sg += S[b * 256 + g * 8 + k];
        Qg += Q[b * 256 + g * 8 + k];
    }
    float cnt8 = (float)scnt[b] * 8.f;
    float D = cnt8 + EPS;                      // matches reference: count*cpg + EPS
    float m = Sg / D;
    float var = (Qg - 2.f * m * Sg + cnt8 * m * m) / D;
    float istd = rsqrtf(var + EPS);
    gmean[tid] = m;      // tid = b*32+g
    gistd[tid] = istd;
}

// ---------- normalize + affine + SiLU: f32 in -> bf16 y ----------
__global__ __launch_bounds__(256) void norm_silu_kernel(const float* __restrict__ xin,
                                                        const int* __restrict__ batch_id,
                                                        const float* __restrict__ gmean, const float* __restrict__ gistd,
                                                        const float* __restrict__ w, const float* __restrict__ bias,
                                                        u16* __restrict__ yout) {
    int tid = threadIdx.x;
    int n = blockIdx.x * 8 + (tid >> 5);
    int g = tid & 31;
    int c0 = g * 8;
    int b = batch_id[n];
    float m = gmean[b * 32 + g], is = gistd[b * 32 + g];
    u16x8 o;
#pragma unroll
    for (int k = 0; k < 8; k++) {
        float v = (xin[(size_t)n * 256 + c0 + k] - m) * is;
        v = v * w[c0 + k] + bias[c0 + k];
        v = v / (1.f + expf(-v));
        o[k] = f2bf(v);
    }
    *(u16x8*)&yout[(size_t)n * 256 + c0] = o;
}

// ---------- CSR build ----------
__global__ __launch_bounds__(256) void hist_kernel(const int* __restrict__ ei, const int* __restrict__ et,
                                                   int* __restrict__ hist) {
    int e = blockIdx.x * 256 + threadIdx.x;
    if (e >= E_EDGES) return;
    int s = ei[e] * 7 + et[e];
    atomicAdd(&hist[s], 1);
}

__global__ __launch_bounds__(512) void scan1_kernel(const int* __restrict__ hist, int* __restrict__ partials) {
    __shared__ int sd[512];
    int i = blockIdx.x * 512 + threadIdx.x;
    sd[threadIdx.x] = hist[i];
    __syncthreads();
    for (int off = 256; off > 0; off >>= 1) {
        if (threadIdx.x < off) sd[threadIdx.x] += sd[threadIdx.x + off];
        __syncthreads();
    }
    if (threadIdx.x == 0) partials[blockIdx.x] = sd[0];
}

__global__ __launch_bounds__(1024) void scan2_kernel(int* __restrict__ partials) {
    __shared__ int sd[1024];
    int t = threadIdx.x;
    int v = (t < 896) ? partials[t] : 0;
    sd[t] = v;
    __syncthreads();
    for (int off = 1; off < 1024; off <<= 1) {
        int u = (t >= off) ? sd[t - off] : 0;
        __syncthreads();
        sd[t] += u;
        __syncthreads();
    }
    if (t < 896) partials[t] = sd[t] - v;   // exclusive
}

// In-place: reads hist[i], writes offsets over the same buffer.
__global__ __launch_bounds__(512) void scan3_kernel(int* __restrict__ hist_offs, const int* __restrict__ partials,
                                                    int* __restrict__ cursor) {
    __shared__ int sd[512];
    int t = threadIdx.x;
    int i = blockIdx.x * 512 + t;
    int c = hist_offs[i];
    sd[t] = c;
    __syncthreads();
    for (int off = 1; off < 512; off <<= 1) {
        int u = (t >= off) ? sd[t - off] : 0;
        __syncthreads();
        sd[t] += u;
        __syncthreads();
    }
    int o = partials[blockIdx.x] + sd[t] - c;
    hist_offs[i] = o;
    cursor[i] = o;
}

__global__ __launch_bounds__(256) void fill_kernel(const int* __restrict__ ei, const int* __restrict__ et,
                                                   int* __restrict__ cursor, int* __restrict__ elist) {
    int e = blockIdx.x * 256 + threadIdx.x;
    if (e >= E_EDGES) return;
    int s = ei[e] * 7 + et[e];
    int p = atomicAdd(&cursor[s], 1);
    if (p >= 0 && p < E_EDGES) elist[p] = ei[E_EDGES + e];   // col
}

// ---------- fused aggregate + MFMA GEMM ----------
// out[m][n] = sum_k A[m][k] * Wt[n][k]; A[m][t*288+c] built on the fly:
//   c<256  -> sum over edges of segment (m,t) of y[col][c]
//   256..262 -> one-hot node-type counts; 263..287 -> 0
// mode 0: out = acc + embout[batch_id[m]][n]   (h2 f32, written to d_out)
// mode 1: out = acc + x[m][n]                  (final f32 output)
__global__ __launch_bounds__(512, 2) void gemm_fused_kernel(
    const u16* __restrict__ y, const u16* __restrict__ Bt,
    const int* __restrict__ offs, const int* __restrict__ cursor,
    const int* __restrict__ elist, const int* __restrict__ node_type,
    const int* __restrict__ batch_id, const float* __restrict__ embout,
    const float* __restrict__ xres, float* __restrict__ out, int mode)
{
    __shared__ __align__(16) u16 As[128 * 32];   // 8 KB
    __shared__ __align__(16) u16 Bs[256 * 32];   // 16 KB
    int tid = threadIdx.x;
    int lane = tid & 63, w = tid >> 6;
    int wm = w >> 2, wn = w & 3;           // 2 x 4 wave grid; wave tile 64(m) x 64(n)
    int lm = lane & 15, lq = lane >> 4;
    int m0 = blockIdx.x * 128;

    f32x4 acc[4][4];
    f32x4 zz = {0.f, 0.f, 0.f, 0.f};
#pragma unroll
    for (int i = 0; i < 4; i++)
#pragma unroll
        for (int j = 0; j < 4; j++) acc[i][j] = zz;

    int ar = tid >> 2, aq = tid & 3;       // A-build: row (0..127), 8-ch quarter

    for (int kk = 0; kk < GK; kk += 32) {
        int t = kk / TSTRIDE;              // chunks never straddle types (288 % 32 == 0)
        int c0 = kk - t * TSTRIDE;
        __syncthreads();
        // stage B tile 256x32 (Bt ~1 MB, L2-resident)
#pragma unroll
        for (int i2 = 0; i2 < 2; i2++) {
            int q = tid + i2 * 512;
            int row = q >> 2, k8 = q & 3;
            *(u16x8*)&Bs[q * 8] = *(const u16x8*)&Bt[(size_t)row * GK + kk + k8 * 8];
        }
        // build A chunk: segment (m0+ar, t), channels [c0+aq*8, c0+aq*8+8)
        int s = (m0 + ar) * 7 + t;
        int start = offs[s], end = cursor[s];
        float a8[8] = {0.f,0.f,0.f,0.f,0.f,0.f,0.f,0.f};
        if (c0 < 256) {
            int cbase = c0 + aq * 8;
            for (int e = start; e < end; e++) {
                int col = elist[e];
                u16x8 v = *(const u16x8*)&y[(size_t)col * 256 + cbase];
#pragma unroll
                for (int j = 0; j < 8; j++) a8[j] += bf2f(v[j]);
            }
        } else if (aq == 0) {
            for (int e = start; e < end; e++) {
                int nt = node_type[elist[e]];
#pragma unroll
                for (int j = 0; j < 7; j++) a8[j] += (nt == j) ? 1.f : 0.f;
            }
        }
        u16x8 o;
#pragma unroll
        for (int j = 0; j < 8; j++) o[j] = f2bf(a8[j]);
        *(u16x8*)&As[ar * 32 + aq * 8] = o;
        __syncthreads();
        bf16x8 a[4], b[4];
#pragma unroll
        for (int i = 0; i < 4; i++) a[i] = *(const bf16x8*)&As[(wm * 64 + i * 16 + lm) * 32 + lq * 8];
#pragma unroll
        for (int j = 0; j < 4; j++) b[j] = *(const bf16x8*)&Bs[(wn * 64 + j * 16 + lm) * 32 + lq * 8];
#pragma unroll
        for (int i = 0; i < 4; i++)
#pragma unroll
            for (int j = 0; j < 4; j++)
                acc[i][j] = __builtin_amdgcn_mfma_f32_16x16x32_bf16(a[i], b[j], acc[i][j], 0, 0, 0);
    }

#pragma unroll
    for (int i = 0; i < 4; i++) {
#pragma unroll
        for (int r = 0; r < 4; r++) {
            size_t m = (size_t)m0 + wm * 64 + i * 16 + lq * 4 + r;
            float addv[4];
            if (mode == 0) {
                int b = batch_id[m];
#pragma unroll
                for (int j = 0; j < 4; j++) addv[j] = embout[b * 256 + wn * 64 + j * 16 + lm];
            } else {
#pragma unroll
                for (int j = 0; j < 4; j++) addv[j] = xres[m * 256 + wn * 64 + j * 16 + lm];
            }
#pragma unroll
            for (int j = 0; j < 4; j++) {
                int n = wn * 64 + j * 16 + lm;
                out[m * 256 + n] = acc[i][j][r] + addv[j];
            }
        }
    }
}

// ---------- host ----------
extern "C" void kernel_launch(void* const* d_in, const int* in_sizes, int n_in,
                              void* d_out, int out_size, void* d_ws, size_t ws_size,
                              hipStream_t stream) {
    // All float tensors are FLOAT32 (reference uses jnp.float32 throughout).
    const float* x    = (const float*)d_in[0];
    const float* emb  = (const float*)d_in[1];
    const int* bid    = (const int*)d_in[2];
    const int* ei     = (const int*)d_in[3];
    const int* et     = (const int*)d_in[4];
    const int* ntp    = (const int*)d_in[5];
    const float* gn1w = (const float*)d_in[6];
    const float* gn1b = (const float*)d_in[7];
    const float* w1   = (const float*)d_in[8];
    const float* embw = (const float*)d_in[9];
    const float* embb = (const float*)d_in[10];
    const float* gn2w = (const float*)d_in[11];
    const float* gn2b = (const float*)d_in[12];
    const float* w2   = (const float*)d_in[13];
    float* out = (float*)d_out;

    char* p = (char*)d_ws;
    size_t off = 0;
    auto nxt = [&](size_t bytes) -> void* {
        void* r = p + off;
        off += (bytes + 255) & ~(size_t)255;
        return r;
    };
    // ws budget ~43 MB
    u16*   y       = (u16*)nxt((size_t)N_NODES * 256 * 2);     // 33.5 MB (bf16 stage)
    u16*   Wt1     = (u16*)nxt((size_t)256 * GK * 2);          // 1.03 MB
    u16*   Wt2     = (u16*)nxt((size_t)256 * GK * 2);          // 1.03 MB
    float* embout  = (float*)nxt(8 * 256 * 4);
    float* S       = (float*)nxt(2048 * 4);
    float* Q       = (float*)nxt(2048 * 4);
    float* gmean   = (float*)nxt(256 * 4);
    float* gistd   = (float*)nxt(256 * 4);
    int*   offs    = (int*)nxt((size_t)NSEG * 4);              // hist, then offsets in place
    int*   cursor  = (int*)nxt((size_t)NSEG * 4);
    int*   parts   = (int*)nxt(1024 * 4);
    int*   elist   = (int*)nxt((size_t)E_EDGES * 4);
    float* h2      = out;   // d_out doubles as h2 (dead before final write)
    (void)ws_size; (void)in_sizes; (void)n_in; (void)out_size;

    // 1. zero hist + S/Q
    zero_kernel<<<1792, 256, 0, stream>>>(offs, S, Q);
    // 2. weight transpose/pad (f32->bf16) + emb GEMM
    prep_kernel<<<4033, 256, 0, stream>>>(w1, w2, Wt1, Wt2, emb, embw, embb, embout);
    // 3-5. GN1 + SiLU -> y
    stats_kernel<<<1024, 256, 0, stream>>>(x, bid, S, Q);
    finalize_kernel<<<1, 256, 0, stream>>>(bid, S, Q, gmean, gistd);
    norm_silu_kernel<<<8192, 256, 0, stream>>>(x, bid, gmean, gistd, gn1w, gn1b, y);
    // 6-10. CSR build (shared by both convs)
    hist_kernel<<<1792, 256, 0, stream>>>(ei, et, offs);
    scan1_kernel<<<896, 512, 0, stream>>>(offs, parts);
    scan2_kernel<<<1, 1024, 0, stream>>>(parts);
    scan3_kernel<<<896, 512, 0, stream>>>(offs, parts, cursor);
    fill_kernel<<<1792, 256, 0, stream>>>(ei, et, cursor, elist);
    // 11. conv1: fused aggregate+GEMM(+emb) -> h2 (in d_out)
    gemm_fused_kernel<<<512, 512, 0, stream>>>(y, Wt1, offs, cursor, elist, ntp, bid, embout, x, h2, 0);
    // 12-14. GN2 + SiLU -> y
    zero_sq_kernel<<<8, 256, 0, stream>>>(S, Q);
    stats_kernel<<<1024, 256, 0, stream>>>(h2, bid, S, Q);
    finalize_kernel<<<1, 256, 0, stream>>>(bid, S, Q, gmean, gistd);
    norm_silu_kernel<<<8192, 256, 0, stream>>>(h2, bid, gmean, gistd, gn2w, gn2b, y);
    // 15. conv2: fused aggregate+GEMM(+x skip) -> out
    gemm_fused_kernel<<<512, 512, 0, stream>>>(y, Wt2, offs, cursor, elist, ntp, bid, embout, x, out, 1);
}

// Round 8
// 804.134 us; speedup vs baseline: 6.8221x; 1.0923x over previous
//
#include <hip/hip_runtime.h>
#include <math.h>

// ---------- Problem constants ----------
#define N_NODES 65536
#define B_GR    8
#define EMB_N   512
#define E_EDGES 458752     // N * 7
#define NSEG    458752     // N * 7 segments (row*7 + etype)
#define TSTRIDE 288        // per-type padded K (263 used: 256 feat + 7 onehot)
#define GK      2016       // 7 * 288, multiple of 32
#define EPS     1e-5f

typedef unsigned short u16;
typedef unsigned int   u32;
typedef __bf16 bf16x8 __attribute__((ext_vector_type(8)));
typedef float  f32x4  __attribute__((ext_vector_type(4)));
typedef u16    u16x8  __attribute__((ext_vector_type(8)));

__device__ __forceinline__ float bf2f(u16 u) {
    u32 x = ((u32)u) << 16; float f; __builtin_memcpy(&f, &x, 4); return f;
}
__device__ __forceinline__ u16 f2bf(float f) {
    u32 x; __builtin_memcpy(&x, &f, 4);
    u32 r = x + 0x7fffu + ((x >> 16) & 1u);
    return (u16)(r >> 16);
}

// XOR swizzle: k-slot 'k8' of row 'row' lives at slot k8 ^ ((row>>1)&3).
// Frag reads (16 consecutive rows, fixed lq) hit 8 distinct bank-starts
// x 2 lanes = 2-way (free, m136); writes stay a permutation per row.
#define SW(row, k8) ((k8) ^ (((row) >> 1) & 3))

// ---------- zero scratch (hist + S + Q) ----------
__global__ __launch_bounds__(256) void zero_kernel(int* __restrict__ hist,
                                                   float* __restrict__ S, float* __restrict__ Q) {
    int i = blockIdx.x * 256 + threadIdx.x;
    if (i < NSEG) hist[i] = 0;
    if (i < 2048) { S[i] = 0.f; Q[i] = 0.f; }
}
__global__ __launch_bounds__(256) void zero_sq_kernel(float* __restrict__ S, float* __restrict__ Q) {
    int i = blockIdx.x * 256 + threadIdx.x;
    if (i < 2048) { S[i] = 0.f; Q[i] = 0.f; }
}

// ---------- weight transpose+pad (f32 -> bf16)  and  emb GEMM ----------
// Wt[n][t*288+c] = bf16(W[(t*263+c)*256 + n])  (c<263, else 0)
__global__ __launch_bounds__(256) void prep_kernel(
    const float* __restrict__ w1, const float* __restrict__ w2,
    u16* __restrict__ Wt1, u16* __restrict__ Wt2,
    const float* __restrict__ emb, const float* __restrict__ embw,
    const float* __restrict__ embb, float* __restrict__ embout)
{
    int bid = blockIdx.x, tid = threadIdx.x;
    if (bid < 4032) {
        const float* Win = (bid < 2016) ? w1 : w2;
        u16* Wt = (bid < 2016) ? Wt1 : Wt2;
        int idx = (bid % 2016) * 256 + tid;          // over 256*2016 outputs
        int n = idx / GK;
        int k = idx - n * GK;
        int t = k / TSTRIDE;
        int c = k - t * TSTRIDE;
        u16 v = (c < 263) ? f2bf(Win[(size_t)(t * 263 + c) * 256 + n]) : (u16)0;
        Wt[idx] = v;
    } else {
        __shared__ float semb[B_GR * EMB_N];
        for (int i = tid; i < B_GR * EMB_N; i += 256) {
            float e = emb[i];
            semb[i] = e / (1.f + expf(-e));
        }
        __syncthreads();
        float acc[8];
        float bb = embb[tid];
#pragma unroll
        for (int b = 0; b < 8; b++) acc[b] = bb;
        for (int k = 0; k < EMB_N; k++) {
            float wv = embw[k * 256 + tid];
#pragma unroll
            for (int b = 0; b < 8; b++) acc[b] += semb[b * EMB_N + k] * wv;
        }
#pragma unroll
        for (int b = 0; b < 8; b++) embout[b * 256 + tid] = acc[b];
    }
}

// ---------- group-norm stats: per (batch, channel) sums ----------
__global__ __launch_bounds__(256) void stats_kernel(const float* __restrict__ xin,
                                                    const int* __restrict__ batch_id,
                                                    float* __restrict__ S, float* __restrict__ Q) {
    int c = threadIdx.x;
    int n0 = blockIdx.x * 64;
    float s = 0.f, q = 0.f;
    int bcur = batch_id[n0];
    for (int r = 0; r < 64; r++) {
        int n = n0 + r;
        int b = batch_id[n];
        if (b != bcur) {
            atomicAdd(&S[bcur * 256 + c], s);
            atomicAdd(&Q[bcur * 256 + c], q);
            s = 0.f; q = 0.f; bcur = b;
        }
        float v = xin[(size_t)n * 256 + c];
        s += v;
        q = fmaf(v, v, q);
    }
    atomicAdd(&S[bcur * 256 + c], s);
    atomicAdd(&Q[bcur * 256 + c], q);
}

// ---------- finalize: counts + per-(b,group) mean / inv_std ----------
__global__ __launch_bounds__(256) void finalize_kernel(const int* __restrict__ batch_id,
                                                       const float* __restrict__ S, const float* __restrict__ Q,
                                                       float* __restrict__ gmean, float* __restrict__ gistd) {
    __shared__ int scnt[8];
    int tid = threadIdx.x;
    if (tid < 8) scnt[tid] = 0;
    __syncthreads();
    int c0=0,c1=0,c2=0,c3=0,c4=0,c5=0,c6=0,c7=0;
    for (int i = tid; i < N_NODES; i += 256) {
        int b = batch_id[i];
        c0 += (b==0); c1 += (b==1); c2 += (b==2); c3 += (b==3);
        c4 += (b==4); c5 += (b==5); c6 += (b==6); c7 += (b==7);
    }
    atomicAdd(&scnt[0], c0); atomicAdd(&scnt[1], c1); atomicAdd(&scnt[2], c2); atomicAdd(&scnt[3], c3);
    atomicAdd(&scnt[4], c4); atomicAdd(&scnt[5], c5); atomicAdd(&scnt[6], c6); atomicAdd(&scnt[7], c7);
    __syncthreads();
    int b = tid >> 5, g = tid & 31;
    float Sg = 0.f, Qg = 0.f;
#pragma unroll
    for (int k = 0; k < 8; k++) {
        Sg += S[b * 256 + g * 8 + k];
        Qg += Q[b * 256 + g * 8 + k];
    }
    float cnt8 = (float)scnt[b] * 8.f;
    float D = cnt8 + EPS;                      // matches reference: count*cpg + EPS
    float m = Sg / D;
    float var = (Qg - 2.f * m * Sg + cnt8 * m * m) / D;
    float istd = rsqrtf(var + EPS);
    gmean[tid] = m;      // tid = b*32+g
    gistd[tid] = istd;
}

// ---------- normalize + affine + SiLU: f32 in -> bf16 y ----------
__global__ __launch_bounds__(256) void norm_silu_kernel(const float* __restrict__ xin,
                                                        const int* __restrict__ batch_id,
                                                        const float* __restrict__ gmean, const float* __restrict__ gistd,
                                                        const float* __restrict__ w, const float* __restrict__ bias,
                                                        u16* __restrict__ yout) {
    int tid = threadIdx.x;
    int n = blockIdx.x * 8 + (tid >> 5);
    int g = tid & 31;
    int c0 = g * 8;
    int b = batch_id[n];
    float m = gmean[b * 32 + g], is = gistd[b * 32 + g];
    u16x8 o;
#pragma unroll
    for (int k = 0; k < 8; k++) {
        float v = (xin[(size_t)n * 256 + c0 + k] - m) * is;
        v = v * w[c0 + k] + bias[c0 + k];
        v = v / (1.f + expf(-v));
        o[k] = f2bf(v);
    }
    *(u16x8*)&yout[(size_t)n * 256 + c0] = o;
}

// ---------- CSR build ----------
__global__ __launch_bounds__(256) void hist_kernel(const int* __restrict__ ei, const int* __restrict__ et,
                                                   int* __restrict__ hist) {
    int e = blockIdx.x * 256 + threadIdx.x;
    if (e >= E_EDGES) return;
    int s = ei[e] * 7 + et[e];
    atomicAdd(&hist[s], 1);
}

__global__ __launch_bounds__(512) void scan1_kernel(const int* __restrict__ hist, int* __restrict__ partials) {
    __shared__ int sd[512];
    int i = blockIdx.x * 512 + threadIdx.x;
    sd[threadIdx.x] = hist[i];
    __syncthreads();
    for (int off = 256; off > 0; off >>= 1) {
        if (threadIdx.x < off) sd[threadIdx.x] += sd[threadIdx.x + off];
        __syncthreads();
    }
    if (threadIdx.x == 0) partials[blockIdx.x] = sd[0];
}

__global__ __launch_bounds__(1024) void scan2_kernel(int* __restrict__ partials) {
    __shared__ int sd[1024];
    int t = threadIdx.x;
    int v = (t < 896) ? partials[t] : 0;
    sd[t] = v;
    __syncthreads();
    for (int off = 1; off < 1024; off <<= 1) {
        int u = (t >= off) ? sd[t - off] : 0;
        __syncthreads();
        sd[t] += u;
        __syncthreads();
    }
    if (t < 896) partials[t] = sd[t] - v;   // exclusive
}

// In-place: reads hist[i], writes offsets over the same buffer.
__global__ __launch_bounds__(512) void scan3_kernel(int* __restrict__ hist_offs, const int* __restrict__ partials,
                                                    int* __restrict__ cursor) {
    __shared__ int sd[512];
    int t = threadIdx.x;
    int i = blockIdx.x * 512 + t;
    int c = hist_offs[i];
    sd[t] = c;
    __syncthreads();
    for (int off = 1; off < 512; off <<= 1) {
        int u = (t >= off) ? sd[t - off] : 0;
        __syncthreads();
        sd[t] += u;
        __syncthreads();
    }
    int o = partials[blockIdx.x] + sd[t] - c;
    hist_offs[i] = o;
    cursor[i] = o;
}

__global__ __launch_bounds__(256) void fill_kernel(const int* __restrict__ ei, const int* __restrict__ et,
                                                   int* __restrict__ cursor, int* __restrict__ elist) {
    int e = blockIdx.x * 256 + threadIdx.x;
    if (e >= E_EDGES) return;
    int s = ei[e] * 7 + et[e];
    int p = atomicAdd(&cursor[s], 1);
    if (p >= 0 && p < E_EDGES) elist[p] = ei[E_EDGES + e];   // col
}

// ---------- fused aggregate + MFMA GEMM (BM=64, BN=256, 256 thr) ----------
// out[m][n] = sum_k A[m][k] * Wt[n][k]; A built on the fly per 32-chunk.
// Per type: CSR cols cached once in registers (<=4; overflow loop for rare
// bigger segments); next chunk's y-gather + B-tile loads issued between the
// ds_reads and MFMA of the current chunk to hide global latency.
// ALL y-gathers index y with the FULL offset col*256 + chunk*32 + aq*8
// (round 7 bug: a pre-offset yq base double-counted aq*8).
// mode 0: out = acc + embout[batch_id[m]][n]   (h2 f32, in d_out)
// mode 1: out = acc + x[m][n]                  (final f32 output)
__global__ __launch_bounds__(256) void gemm_fused_kernel(
    const u16* __restrict__ y, const u16* __restrict__ Bt,
    const int* __restrict__ offs, const int* __restrict__ cursor,
    const int* __restrict__ elist, const int* __restrict__ node_type,
    const int* __restrict__ batch_id, const float* __restrict__ embout,
    const float* __restrict__ xres, float* __restrict__ out, int mode)
{
    __shared__ __align__(16) u16 As[64 * 32];    // 4 KB
    __shared__ __align__(16) u16 Bs[256 * 32];   // 16 KB
    int tid = threadIdx.x;
    int lane = tid & 63;
    int wn = tid >> 6;                     // 4 waves, each 64(m) x 64(n)
    int lm = lane & 15, lq = lane >> 4;
    int m0 = blockIdx.x * 64;
    int ar = tid >> 2, aq = tid & 3;       // A-build: row (0..63), 8-ch quarter

    f32x4 acc[4][4];
    f32x4 zz = {0.f, 0.f, 0.f, 0.f};
#pragma unroll
    for (int i = 0; i < 4; i++)
#pragma unroll
        for (int j = 0; j < 4; j++) acc[i][j] = zz;

    const u16* btp = Bt + (size_t)ar * GK + aq * 8;   // rows ar + i2*64, slot aq

    float a8[8];
    u16x8 breg[4];

    for (int t = 0; t < 7; t++) {
        // ---- per-type CSR state (loaded ONCE per type) ----
        int s = (m0 + ar) * 7 + t;
        int st = offs[s], en = cursor[s];
        int cnt = en - st;
        int col[4];
#pragma unroll
        for (int u = 0; u < 4; u++) col[u] = (cnt > u) ? elist[st + u] : -1;

        // ---- prologue: gather chunk 0 + B chunk 0 ----
#pragma unroll
        for (int j = 0; j < 8; j++) a8[j] = 0.f;
        {
            int cb = aq * 8;               // chunk 0: channels [aq*8, aq*8+8)
#pragma unroll
            for (int u = 0; u < 4; u++)
                if (col[u] >= 0) {
                    u16x8 v = *(const u16x8*)&y[(size_t)col[u] * 256 + cb];
#pragma unroll
                    for (int j = 0; j < 8; j++) a8[j] += bf2f(v[j]);
                }
            if (cnt > 4)
                for (int e = st + 4; e < en; e++) {
                    u16x8 v = *(const u16x8*)&y[(size_t)elist[e] * 256 + cb];
#pragma unroll
                    for (int j = 0; j < 8; j++) a8[j] += bf2f(v[j]);
                }
        }
        {
            int kb = t * TSTRIDE;
#pragma unroll
            for (int i2 = 0; i2 < 4; i2++) breg[i2] = *(const u16x8*)&btp[(size_t)i2 * 64 * GK + kb];
        }

#pragma unroll
        for (int c9 = 0; c9 < 9; c9++) {
            __syncthreads();
            // ---- write As (pack a8) + Bs (from breg): pure LDS region ----
            u16x8 o;
#pragma unroll
            for (int j = 0; j < 8; j++) o[j] = f2bf(a8[j]);
            *(u16x8*)&As[ar * 32 + SW(ar, aq) * 8] = o;
#pragma unroll
            for (int i2 = 0; i2 < 4; i2++) {
                int row = ar + i2 * 64;
                *(u16x8*)&Bs[row * 32 + SW(row, aq) * 8] = breg[i2];
            }
            __syncthreads();
            // ---- fragments ----
            bf16x8 a[4], b[4];
#pragma unroll
            for (int i = 0; i < 4; i++) {
                int ra = i * 16 + lm;
                a[i] = *(const bf16x8*)&As[ra * 32 + SW(ra, lq) * 8];
            }
#pragma unroll
            for (int j = 0; j < 4; j++) {
                int rb = wn * 64 + j * 16 + lm;
                b[j] = *(const bf16x8*)&Bs[rb * 32 + SW(rb, lq) * 8];
            }
            // ---- prefetch next chunk (registers only; overlaps MFMA) ----
            u16x8 gv[4];
            int nt4[4];
#pragma unroll
            for (int j = 0; j < 8; j++) a8[j] = 0.f;
            if (c9 < 7) {             // next = feature chunk c9+1
                int cb = (c9 + 1) * 32 + aq * 8;
#pragma unroll
                for (int u = 0; u < 4; u++)
                    if (col[u] >= 0) gv[u] = *(const u16x8*)&y[(size_t)col[u] * 256 + cb];
                int kb = t * TSTRIDE + (c9 + 1) * 32;
#pragma unroll
                for (int i2 = 0; i2 < 4; i2++) breg[i2] = *(const u16x8*)&btp[(size_t)i2 * 64 * GK + kb];
            } else if (c9 == 7) {     // next = one-hot chunk
                if (aq == 0) {
#pragma unroll
                    for (int u = 0; u < 4; u++)
                        if (col[u] >= 0) nt4[u] = node_type[col[u]];
                }
                int kb = t * TSTRIDE + 8 * 32;
#pragma unroll
                for (int i2 = 0; i2 < 4; i2++) breg[i2] = *(const u16x8*)&btp[(size_t)i2 * 64 * GK + kb];
            }
            // ---- MFMA ----
#pragma unroll
            for (int i = 0; i < 4; i++)
#pragma unroll
                for (int j = 0; j < 4; j++)
                    acc[i][j] = __builtin_amdgcn_mfma_f32_16x16x32_bf16(a[i], b[j], acc[i][j], 0, 0, 0);
            // ---- fold prefetched gather into a8 ----
            if (c9 < 7) {
#pragma unroll
                for (int u = 0; u < 4; u++)
                    if (col[u] >= 0) {
#pragma unroll
                        for (int j = 0; j < 8; j++) a8[j] += bf2f(gv[u][j]);
                    }
                if (cnt > 4) {
                    int cb = (c9 + 1) * 32 + aq * 8;
                    for (int e = st + 4; e < en; e++) {
                        u16x8 v = *(const u16x8*)&y[(size_t)elist[e] * 256 + cb];
#pragma unroll
                        for (int j = 0; j < 8; j++) a8[j] += bf2f(v[j]);
                    }
                }
            } else if (c9 == 7) {
                if (aq == 0) {
#pragma unroll
                    for (int u = 0; u < 4; u++)
                        if (col[u] >= 0) {
#pragma unroll
                            for (int j = 0; j < 7; j++) a8[j] += (nt4[u] == j) ? 1.f : 0.f;
                        }
                    if (cnt > 4)
                        for (int e = st + 4; e < en; e++) {
                            int nt = node_type[elist[e]];
#pragma unroll
                            for (int j = 0; j < 7; j++) a8[j] += (nt == j) ? 1.f : 0.f;
                        }
                }
            }
        }
    }

    // ---- epilogue ----
#pragma unroll
    for (int i = 0; i < 4; i++) {
#pragma unroll
        for (int r = 0; r < 4; r++) {
            size_t m = (size_t)m0 + i * 16 + lq * 4 + r;
            float addv[4];
            if (mode == 0) {
                int b = batch_id[m];
#pragma unroll
                for (int j = 0; j < 4; j++) addv[j] = embout[b * 256 + wn * 64 + j * 16 + lm];
            } else {
#pragma unroll
                for (int j = 0; j < 4; j++) addv[j] = xres[m * 256 + wn * 64 + j * 16 + lm];
            }
#pragma unroll
            for (int j = 0; j < 4; j++) {
                int n = wn * 64 + j * 16 + lm;
                out[m * 256 + n] = acc[i][j][r] + addv[j];
            }
        }
    }
}

// ---------- host ----------
extern "C" void kernel_launch(void* const* d_in, const int* in_sizes, int n_in,
                              void* d_out, int out_size, void* d_ws, size_t ws_size,
                              hipStream_t stream) {
    // All float tensors are FLOAT32 (reference uses jnp.float32 throughout).
    const float* x    = (const float*)d_in[0];
    const float* emb  = (const float*)d_in[1];
    const int* bid    = (const int*)d_in[2];
    const int* ei     = (const int*)d_in[3];
    const int* et     = (const int*)d_in[4];
    const int* ntp    = (const int*)d_in[5];
    const float* gn1w = (const float*)d_in[6];
    const float* gn1b = (const float*)d_in[7];
    const float* w1   = (const float*)d_in[8];
    const float* embw = (const float*)d_in[9];
    const float* embb = (const float*)d_in[10];
    const float* gn2w = (const float*)d_in[11];
    const float* gn2b = (const float*)d_in[12];
    const float* w2   = (const float*)d_in[13];
    float* out = (float*)d_out;

    char* p = (char*)d_ws;
    size_t off = 0;
    auto nxt = [&](size_t bytes) -> void* {
        void* r = p + off;
        off += (bytes + 255) & ~(size_t)255;
        return r;
    };
    // ws budget ~43 MB
    u16*   y       = (u16*)nxt((size_t)N_NODES * 256 * 2);     // 33.5 MB (bf16 stage)
    u16*   Wt1     = (u16*)nxt((size_t)256 * GK * 2);          // 1.03 MB
    u16*   Wt2     = (u16*)nxt((size_t)256 * GK * 2);          // 1.03 MB
    float* embout  = (float*)nxt(8 * 256 * 4);
    float* S       = (float*)nxt(2048 * 4);
    float* Q       = (float*)nxt(2048 * 4);
    float* gmean   = (float*)nxt(256 * 4);
    float* gistd   = (float*)nxt(256 * 4);
    int*   offs    = (int*)nxt((size_t)NSEG * 4);              // hist, then offsets in place
    int*   cursor  = (int*)nxt((size_t)NSEG * 4);
    int*   parts   = (int*)nxt(1024 * 4);
    int*   elist   = (int*)nxt((size_t)E_EDGES * 4);
    float* h2      = out;   // d_out doubles as h2 (dead before final write)
    (void)ws_size; (void)in_sizes; (void)n_in; (void)out_size;

    // 1. zero hist + S/Q
    zero_kernel<<<1792, 256, 0, stream>>>(offs, S, Q);
    // 2. weight transpose/pad (f32->bf16) + emb GEMM
    prep_kernel<<<4033, 256, 0, stream>>>(w1, w2, Wt1, Wt2, emb, embw, embb, embout);
    // 3-5. GN1 + SiLU -> y
    stats_kernel<<<1024, 256, 0, stream>>>(x, bid, S, Q);
    finalize_kernel<<<1, 256, 0, stream>>>(bid, S, Q, gmean, gistd);
    norm_silu_kernel<<<8192, 256, 0, stream>>>(x, bid, gmean, gistd, gn1w, gn1b, y);
    // 6-10. CSR build (shared by both convs)
    hist_kernel<<<1792, 256, 0, stream>>>(ei, et, offs);
    scan1_kernel<<<896, 512, 0, stream>>>(offs, parts);
    scan2_kernel<<<1, 1024, 0, stream>>>(parts);
    scan3_kernel<<<896, 512, 0, stream>>>(offs, parts, cursor);
    fill_kernel<<<1792, 256, 0, stream>>>(ei, et, cursor, elist);
    // 11. conv1: fused aggregate+GEMM(+emb) -> h2 (in d_out)
    gemm_fused_kernel<<<1024, 256, 0, stream>>>(y, Wt1, offs, cursor, elist, ntp, bid, embout, x, h2, 0);
    // 12-14. GN2 + SiLU -> y
    zero_sq_kernel<<<8, 256, 0, stream>>>(S, Q);
    stats_kernel<<<1024, 256, 0, stream>>>(h2, bid, S, Q);
    finalize_kernel<<<1, 256, 0, stream>>>(bid, S, Q, gmean, gistd);
    norm_silu_kernel<<<8192, 256, 0, stream>>>(h2, bid, gmean, gistd, gn2w, gn2b, y);
    // 15. conv2: fused aggregate+GEMM(+x skip) -> out
    gemm_fused_kernel<<<1024, 256, 0, stream>>>(y, Wt2, offs, cursor, elist, ntp, bid, embout, x, out, 1);
}